// Round 1
// baseline (85.864 us; speedup 1.0000x reference)
//
#include <hip/hip_runtime.h>

#define BATCH 4
#define QDIM 1024
#define KDIM 1024
#define EDIM 512
#define H 32
#define VDIM 256
#define QT 16

// 2*log2(e): pre-scale projections so tanh arg becomes exp2 input directly
#define TWO_LOG2E 2.8853900817779268f
#define LOG2E 1.4426950408889634f

// ---------------------------------------------------------------------------
// Kernel 1: q_proj = queries @ Wq, k_proj = keys @ Wk, both scaled by 2*log2e.
// 32 rows per block; thread = (row, group of 4 h). 256 blocks total (128 q + 128 k).
// ---------------------------------------------------------------------------
__global__ __launch_bounds__(256) void proj_kernel(
    const float* __restrict__ qin, const float* __restrict__ kin,
    const float* __restrict__ Wqm, const float* __restrict__ Wkm,
    float* __restrict__ qp, float* __restrict__ kp)
{
    const int nb = 128;
    const bool is_k = blockIdx.x >= nb;
    const float* in = is_k ? kin : qin;
    const float* W  = is_k ? Wkm : Wqm;
    float* outp     = is_k ? kp : qp;
    const int row = (is_k ? (int)blockIdx.x - nb : (int)blockIdx.x) * 32 + ((int)threadIdx.x >> 3);
    const int h4  = ((int)threadIdx.x & 7) * 4;

    const float* inrow = in + (size_t)row * EDIM;
    float ax = 0.f, ay = 0.f, az = 0.f, aw = 0.f;

    for (int e = 0; e < EDIM; e += 4) {
        float4 a4 = *reinterpret_cast<const float4*>(inrow + e);
        float4 w0 = *reinterpret_cast<const float4*>(W + (size_t)(e + 0) * H + h4);
        float4 w1 = *reinterpret_cast<const float4*>(W + (size_t)(e + 1) * H + h4);
        float4 w2 = *reinterpret_cast<const float4*>(W + (size_t)(e + 2) * H + h4);
        float4 w3 = *reinterpret_cast<const float4*>(W + (size_t)(e + 3) * H + h4);
        ax = fmaf(a4.x, w0.x, ax); ay = fmaf(a4.x, w0.y, ay);
        az = fmaf(a4.x, w0.z, az); aw = fmaf(a4.x, w0.w, aw);
        ax = fmaf(a4.y, w1.x, ax); ay = fmaf(a4.y, w1.y, ay);
        az = fmaf(a4.y, w1.z, az); aw = fmaf(a4.y, w1.w, aw);
        ax = fmaf(a4.z, w2.x, ax); ay = fmaf(a4.z, w2.y, ay);
        az = fmaf(a4.z, w2.z, az); aw = fmaf(a4.z, w2.w, aw);
        ax = fmaf(a4.w, w3.x, ax); ay = fmaf(a4.w, w3.y, ay);
        az = fmaf(a4.w, w3.z, az); aw = fmaf(a4.w, w3.w, aw);
    }
    float4 r;
    r.x = ax * TWO_LOG2E; r.y = ay * TWO_LOG2E;
    r.z = az * TWO_LOG2E; r.w = aw * TWO_LOG2E;
    *reinterpret_cast<float4*>(outp + (size_t)row * H + h4) = r;
}

// ---------------------------------------------------------------------------
// Kernel 2: fused scores -> softmax -> PV for a tile of QT=16 query rows.
// grid = B * (Q/QT) = 256 blocks, 512 threads.
// score = sum(wv) - 2 * sum_h wv[h] * rcp(1 + exp2(q'[h] + k'[h]))
// ---------------------------------------------------------------------------
__global__ __launch_bounds__(512) void attn_fused(
    const float* __restrict__ qp, const float* __restrict__ kp,
    const float* __restrict__ values, const float* __restrict__ wv,
    float* __restrict__ out)
{
    __shared__ float attn[QT * KDIM];   // 64 KB; reused as combine buffer in PV
    __shared__ float inv_lds[QT];

    const int tid = (int)threadIdx.x;
    const int b   = (int)blockIdx.x >> 6;
    const int q0  = ((int)blockIdx.x & 63) * QT;
    const float* qrow = qp + (size_t)(b * QDIM + q0) * H;   // wave-uniform

    // sum(wv) — wave-uniform scalar loads
    float sumwv = 0.f;
    #pragma unroll
    for (int h = 0; h < H; ++h) sumwv += wv[h];

    // ---- phase 1: scores + exp (unnormalized attn weights into LDS) ----
    #pragma unroll
    for (int t = 0; t < 2; ++t) {
        const int kk = t * 512 + tid;
        float kreg[H];
        const float* krow = kp + (size_t)(b * KDIM + kk) * H;
        #pragma unroll
        for (int i = 0; i < H / 4; ++i) {
            float4 v = *reinterpret_cast<const float4*>(krow + i * 4);
            kreg[i * 4 + 0] = v.x; kreg[i * 4 + 1] = v.y;
            kreg[i * 4 + 2] = v.z; kreg[i * 4 + 3] = v.w;
        }
        for (int qr = 0; qr < QT; ++qr) {
            float s2 = 0.f;
            #pragma unroll
            for (int h = 0; h < H; ++h) {
                float u = __builtin_amdgcn_exp2f(qrow[qr * H + h] + kreg[h]);
                float rr = __builtin_amdgcn_rcpf(u + 1.f);
                s2 = fmaf(wv[h], rr, s2);
            }
            float score = sumwv - 2.f * s2;
            attn[qr * KDIM + kk] = __builtin_amdgcn_exp2f(score * LOG2E);
        }
    }
    __syncthreads();

    // ---- phase 2: softmax denominators (one 32-lane group per q row) ----
    {
        const int row = tid >> 5;          // 0..15
        const int c0  = tid & 31;
        float s = 0.f;
        #pragma unroll
        for (int j = 0; j < 32; ++j) s += attn[row * KDIM + c0 + j * 32];
        #pragma unroll
        for (int m = 16; m > 0; m >>= 1) s += __shfl_xor(s, m, 64);
        if (c0 == 0) inv_lds[row] = 1.0f / s;
    }
    __syncthreads();

    // ---- phase 3: PV. thread = (k-partition p of 8, 4 value columns) ----
    const int p  = tid >> 6;
    const int c4 = (tid & 63) * 4;
    float4 acc[QT];
    #pragma unroll
    for (int i = 0; i < QT; ++i) { acc[i].x = 0.f; acc[i].y = 0.f; acc[i].z = 0.f; acc[i].w = 0.f; }

    const float* vbase = values + ((size_t)b * KDIM + p * 128) * VDIM + c4;
    for (int i = 0; i < 128; ++i) {
        float4 v = *reinterpret_cast<const float4*>(vbase + (size_t)i * VDIM);
        const int kk = p * 128 + i;
        #pragma unroll
        for (int qr = 0; qr < QT; ++qr) {
            float a = attn[qr * KDIM + kk];
            acc[qr].x = fmaf(a, v.x, acc[qr].x);
            acc[qr].y = fmaf(a, v.y, acc[qr].y);
            acc[qr].z = fmaf(a, v.z, acc[qr].z);
            acc[qr].w = fmaf(a, v.w, acc[qr].w);
        }
    }

    // ---- tree-combine the 8 k-partitions (reuse attn LDS region) ----
    float* buf = attn;
    #pragma unroll
    for (int off = 4; off > 0; off >>= 1) {
        __syncthreads();
        if (p >= off && p < 2 * off) {
            #pragma unroll
            for (int qr = 0; qr < QT; ++qr)
                *reinterpret_cast<float4*>(buf + ((p - off) * QT + qr) * VDIM + c4) = acc[qr];
        }
        __syncthreads();
        if (p < off) {
            #pragma unroll
            for (int qr = 0; qr < QT; ++qr) {
                float4 t = *reinterpret_cast<const float4*>(buf + (p * QT + qr) * VDIM + c4);
                acc[qr].x += t.x; acc[qr].y += t.y; acc[qr].z += t.z; acc[qr].w += t.w;
            }
        }
    }

    if (p == 0) {
        #pragma unroll
        for (int qr = 0; qr < QT; ++qr) {
            float s = inv_lds[qr];
            float4 r = acc[qr];
            r.x *= s; r.y *= s; r.z *= s; r.w *= s;
            *reinterpret_cast<float4*>(out + (size_t)(b * QDIM + q0 + qr) * VDIM + c4) = r;
        }
    }
}

extern "C" void kernel_launch(void* const* d_in, const int* in_sizes, int n_in,
                              void* d_out, int out_size, void* d_ws, size_t ws_size,
                              hipStream_t stream) {
    const float* queries = (const float*)d_in[0];
    const float* keys    = (const float*)d_in[1];
    const float* values  = (const float*)d_in[2];
    const float* Wq      = (const float*)d_in[3];
    const float* Wk      = (const float*)d_in[4];
    const float* wv      = (const float*)d_in[5];
    float* out = (float*)d_out;

    float* qp = (float*)d_ws;                       // [4096][32]
    float* kp = qp + (size_t)BATCH * QDIM * H;      // [4096][32]

    hipLaunchKernelGGL(proj_kernel, dim3(256), dim3(256), 0, stream,
                       queries, keys, Wq, Wk, qp, kp);
    hipLaunchKernelGGL(attn_fused, dim3(256), dim3(512), 0, stream,
                       qp, kp, values, wv, out);
}